// Round 8
// baseline (173.797 us; speedup 1.0000x reference)
//
#include <hip/hip_runtime.h>
#include <hip/hip_bf16.h>

typedef __attribute__((ext_vector_type(8))) short bf16x8;
typedef __attribute__((ext_vector_type(4))) float f32x4;

#define D        256
#define NH       512
#define NT       32               // n-tiles (16 cols each)
#define KT       8                // k-steps (32 each)
#define MT       2                // M-tiles per wave -> 32 rows/wave
#define ROWS_PER_BLOCK 32         // 1 wave per block
#define ROWS_TOTAL (32*8192)      // 262144

typedef __attribute__((address_space(1))) const void GV;
typedef __attribute__((address_space(3))) void LV;

__device__ __forceinline__ short f2bf(float f) {
    union { float f; unsigned u; } v; v.f = f;
    unsigned r = v.u + 0x7FFFu + ((v.u >> 16) & 1u);
    return (short)(r >> 16);
}
__device__ __forceinline__ float rcp_fast(float x) {
    return __builtin_amdgcn_rcpf(x);
}

// Pack We (fp32 [256][512]) into bf16 MFMA B-fragments:
// frag[(nt*8+kt)*64 + lane][j] = We[kt*32 + (lane>>4)*8 + j][nt*16 + (lane&15)]
// Also: bw[n] = (2*be[n], Wr[n]); Ssum = sum(Wr).
__global__ void prepack_B(const float* __restrict__ We, const float* __restrict__ be,
                          const float* __restrict__ Wr,
                          short* __restrict__ Bh, float2* __restrict__ bw,
                          float* __restrict__ Ssum) {
    int i = blockIdx.x * 256 + threadIdx.x;      // 131072 elements
    int k = i >> 9;
    int n = i & 511;
    int nt = n >> 4, c = n & 15;
    int kt = k >> 5, g = (k >> 3) & 3, j = k & 7;
    int idx = (((nt * 8 + kt) * 64) + (g * 16 + c)) * 8 + j;
    Bh[idx] = f2bf(We[i]);
    if (i < 512) bw[i] = make_float2(2.0f * be[i], Wr[i]);
    if (i == 0) {
        float s = 0.0f;
        for (int t = 0; t < 512; ++t) s += Wr[t];
        Ssum[0] = s;
    }
}

// 1-wave blocks, private 8KB LDS dbuf of 4KB half-tiles, counted vmcnt(4).
__global__ __launch_bounds__(64, 4) void softpool_main(
    const float* __restrict__ x, const short* __restrict__ Bh,
    const float2* __restrict__ bw, const float* __restrict__ br,
    const float* __restrict__ Ssum, float* __restrict__ out)
{
    const int lane = threadIdx.x;        // 0..63
    const int c = lane & 15;             // A row-in-tile / C col / B col
    const int g = lane >> 4;             // k-group
    const long row0 = (long)blockIdx.x * ROWS_PER_BLOCK;

    __shared__ short Bl[2][2048];        // 2 x 4KB half-tile buffers

    const short* gB = Bh + lane * 8;

    // Stage half-tile hp (hp = nt*2 + half): 4 x global_load_lds width=16 (1KB each)
    #define STAGE_HP(buf, hp) {                                                \
        const short* _g = gB + (long)(hp) * 2048;                              \
        _Pragma("unroll")                                                      \
        for (int kk = 0; kk < 4; ++kk)                                         \
            __builtin_amdgcn_global_load_lds((GV*)(_g + kk * 512),             \
                (LV*)&Bl[buf][kk * 512], 16, 0, 0);                            \
    }

    #define VM4 asm volatile("s_waitcnt vmcnt(4)" ::: "memory");

    STAGE_HP(0, 0)   // hp=0, in flight during the A HBM loads

    // ---- Load A fragments (2 Mtiles x 8 k-steps), fp32 -> bf16, keep in regs
    bf16x8 a[MT][KT];
    #pragma unroll
    for (int m = 0; m < MT; ++m) {
        const float* xr = x + (row0 + m * 16 + c) * D + g * 8;
        #pragma unroll
        for (int kt = 0; kt < KT; ++kt) {
            float4 v0 = *(const float4*)(xr + kt * 32);
            float4 v1 = *(const float4*)(xr + kt * 32 + 4);
            bf16x8 t;
            t[0] = f2bf(v0.x); t[1] = f2bf(v0.y); t[2] = f2bf(v0.z); t[3] = f2bf(v0.w);
            t[4] = f2bf(v1.x); t[5] = f2bf(v1.y); t[6] = f2bf(v1.z); t[7] = f2bf(v1.w);
            a[m][kt] = t;
        }
    }
    // (compiler drains vmcnt to use A values -> hp=0 also landed)

    float lps[MT][4];
    #pragma unroll
    for (int m = 0; m < MT; ++m)
        #pragma unroll
        for (int r = 0; r < 4; ++r) lps[m][r] = 0.0f;

    f32x4 accA[MT], accB[MT];

    // Compute one half-tile (4 kt) from Bl[buf] into accv; ktb = 0 or 4.
    #define HALF(buf, accv, ktb) {                                             \
        _Pragma("unroll")                                                      \
        for (int kk = 0; kk < 4; ++kk) {                                       \
            bf16x8 b = *(const bf16x8*)&Bl[buf][kk * 512 + lane * 8];          \
            _Pragma("unroll")                                                  \
            for (int m = 0; m < MT; ++m)                                       \
                accv[m] = __builtin_amdgcn_mfma_f32_16x16x32_bf16(             \
                             a[m][(ktb) + kk], b, accv[m], 0, 0, 0);           \
        }                                                                      \
    }

    #define ZERO(accv) {                                                       \
        _Pragma("unroll")                                                      \
        for (int m = 0; m < MT; ++m)                                           \
            _Pragma("unroll")                                                  \
            for (int r = 0; r < 4; ++r) accv[m][r] = 0.0f;                     \
    }

    #define TANH_(accv, ntv) {                                                 \
        float2 bwv = bw[(ntv) * 16 + c];                                       \
        _Pragma("unroll")                                                      \
        for (int m = 0; m < MT; ++m)                                           \
            _Pragma("unroll")                                                  \
            for (int r = 0; r < 4; ++r) {                                      \
                float z = __builtin_fmaf(accv[m][r], 2.0f, bwv.x);             \
                float e = __expf(z);                                           \
                float rr = rcp_fast(e + 1.0f);                                 \
                lps[m][r] = __builtin_fmaf(bwv.y, rr, lps[m][r]);              \
            }                                                                  \
    }

    // ---- Main loop: 16 iterations x 2 nt; always stage 1 half-tile ahead.
    // Queue invariant at each VM4: [cur-half(4 oldest, must land), next-half(4)]
    for (int it = 0; it < 16; ++it) {
        const int hp0 = 4 * it;            // nt = 2*it, half 0 (buf 0)
        STAGE_HP(1, hp0 + 1)
        VM4
        ZERO(accA)
        HALF(0, accA, 0)
        STAGE_HP(0, hp0 + 2)
        VM4
        HALF(1, accA, 4)
        if (it > 0) TANH_(accB, 2 * it - 1)
        STAGE_HP(1, hp0 + 3)
        VM4
        ZERO(accB)
        HALF(0, accB, 0)
        STAGE_HP(0, (hp0 + 4) & 63)        // wraps to 0 on last iter (harmless)
        VM4
        HALF(1, accB, 4)
        TANH_(accA, 2 * it)
    }
    TANH_(accB, 31)

    // ---- Reduce partials over 16 cols; softmax(sigmoid); weighted output
    const float brv = br[0];
    const float S = Ssum[0];
    #pragma unroll
    for (int m = 0; m < MT; ++m) {
        float l0 = lps[m][0], l1 = lps[m][1], l2 = lps[m][2], l3 = lps[m][3];
        #pragma unroll
        for (int off = 1; off < 16; off <<= 1) {
            l0 += __shfl_xor(l0, off, 64);
            l1 += __shfl_xor(l1, off, 64);
            l2 += __shfl_xor(l2, off, 64);
            l3 += __shfl_xor(l3, off, 64);
        }
        float g0 = S - 2.0f * l0 + brv;
        float g1 = S - 2.0f * l1 + brv;
        float g2 = S - 2.0f * l2 + brv;
        float g3 = S - 2.0f * l3 + brv;
        float s0 = rcp_fast(1.0f + __expf(-g0));
        float s1 = rcp_fast(1.0f + __expf(-g1));
        float s2 = rcp_fast(1.0f + __expf(-g2));
        float s3 = rcp_fast(1.0f + __expf(-g3));
        float e0 = __expf(s0), e1 = __expf(s1), e2 = __expf(s2), e3 = __expf(s3);
        float inv = rcp_fast(e0 + e1 + e2 + e3);
        float w0 = e0 * inv, w1 = e1 * inv, w2 = e2 * inv, w3 = e3 * inv;

        // window = rows [wrow, wrow+3]; lane-group g owns window g of this Mtile
        // lane stores cols [c*4 + q*64 ..+3]: 16 lanes -> 256B contiguous runs
        const long wrow = row0 + m * 16 + g * 4;
        const long W = wrow >> 2;
        const float* xw = x + wrow * D + c * 4;
        float* op = out + W * D + c * 4;
        #pragma unroll
        for (int q = 0; q < 4; ++q) {
            float4 r0 = *(const float4*)(xw + 0 * D + q * 64);
            float4 r1 = *(const float4*)(xw + 1 * D + q * 64);
            float4 r2 = *(const float4*)(xw + 2 * D + q * 64);
            float4 r3 = *(const float4*)(xw + 3 * D + q * 64);
            float4 oo;
            oo.x = w0 * r0.x + w1 * r1.x + w2 * r2.x + w3 * r3.x;
            oo.y = w0 * r0.y + w1 * r1.y + w2 * r2.y + w3 * r3.y;
            oo.z = w0 * r0.z + w1 * r1.z + w2 * r2.z + w3 * r3.z;
            oo.w = w0 * r0.w + w1 * r1.w + w2 * r2.w + w3 * r3.w;
            *(float4*)(op + q * 64) = oo;
        }
    }
}

extern "C" void kernel_launch(void* const* d_in, const int* in_sizes, int n_in,
                              void* d_out, int out_size, void* d_ws, size_t ws_size,
                              hipStream_t stream) {
    const float* x  = (const float*)d_in[0];
    const float* We = (const float*)d_in[1];
    const float* be = (const float*)d_in[2];
    const float* Wr = (const float*)d_in[3];
    const float* br = (const float*)d_in[4];
    float* out = (float*)d_out;

    char* ws = (char*)d_ws;
    short*  Bh   = (short*)ws;                    // 262144 B
    float2* bwp  = (float2*)(ws + 262144);        // 4096 B
    float*  Ssum = (float*)(ws + 262144 + 4096);  // 4 B

    prepack_B<<<NH * D / 256, 256, 0, stream>>>(We, be, Wr, Bh, bwp, Ssum);

    const int blocks = ROWS_TOTAL / ROWS_PER_BLOCK;   // 8192
    softpool_main<<<blocks, 64, 0, stream>>>(x, Bh, bwp, br, Ssum, out);
}

// Round 10
// 154.944 us; speedup vs baseline: 1.1217x; 1.1217x over previous
//
#include <hip/hip_runtime.h>
#include <hip/hip_bf16.h>

typedef __attribute__((ext_vector_type(8))) short bf16x8;
typedef __attribute__((ext_vector_type(4))) float f32x4;

#define D        256
#define NH       512
#define NT       32               // n-tiles (16 cols each)
#define KT       8                // k-steps (32 each)
#define MT       4                // M-tiles per wave -> 64 rows/wave
#define ROWS_PER_BLOCK 64         // 1 wave per block
#define ROWS_TOTAL (32*8192)      // 262144

typedef __attribute__((address_space(1))) const void GV;
typedef __attribute__((address_space(3))) void LV;

__device__ __forceinline__ short f2bf(float f) {
    union { float f; unsigned u; } v; v.f = f;
    unsigned r = v.u + 0x7FFFu + ((v.u >> 16) & 1u);
    return (short)(r >> 16);
}
__device__ __forceinline__ float rcp_fast(float x) {
    return __builtin_amdgcn_rcpf(x);
}

// Pack We (fp32 [256][512]) into bf16 MFMA B-fragments:
// frag[(nt*8+kt)*64 + lane][j] = We[kt*32 + (lane>>4)*8 + j][nt*16 + (lane&15)]
// Also: bw[n] = (2*be[n], Wr[n]); Ssum = sum(Wr).
__global__ void prepack_B(const float* __restrict__ We, const float* __restrict__ be,
                          const float* __restrict__ Wr,
                          short* __restrict__ Bh, float2* __restrict__ bw,
                          float* __restrict__ Ssum) {
    int i = blockIdx.x * 256 + threadIdx.x;      // 131072 elements
    int k = i >> 9;
    int n = i & 511;
    int nt = n >> 4, c = n & 15;
    int kt = k >> 5, g = (k >> 3) & 3, j = k & 7;
    int idx = (((nt * 8 + kt) * 64) + (g * 16 + c)) * 8 + j;
    Bh[idx] = f2bf(We[i]);
    if (i < 512) bw[i] = make_float2(2.0f * be[i], Wr[i]);
    if (i == 0) {
        float s = 0.0f;
        for (int t = 0; t < 512; ++t) s += Wr[t];
        Ssum[0] = s;
    }
}

// 1-wave blocks; 4-deep half-tile (4KB) LDS ring; counted vmcnt(12), never 0.
__global__ __launch_bounds__(64, 2) void softpool_main(
    const float* __restrict__ x, const short* __restrict__ Bh,
    const float2* __restrict__ bw, const float* __restrict__ br,
    const float* __restrict__ Ssum, float* __restrict__ out)
{
    const int lane = threadIdx.x;        // 0..63
    const int c = lane & 15;             // A row-in-tile / C col / B col
    const int g = lane >> 4;             // k-group
    const long row0 = (long)blockIdx.x * ROWS_PER_BLOCK;

    __shared__ short Bl[4][2048];        // 4 x 4KB half-tile ring

    const short* gB = Bh + lane * 8;

    // Stage half-tile h (h = nt*2 + half) into ring buffer `buf` (compile-time).
    // 4 x global_load_lds width=16 (1KB each).
    #define STAGE_HP(buf, h) {                                                 \
        const short* _g = gB + (long)((h) & 63) * 2048;                        \
        _Pragma("unroll")                                                      \
        for (int kk = 0; kk < 4; ++kk)                                         \
            __builtin_amdgcn_global_load_lds((GV*)(_g + kk * 512),             \
                (LV*)&Bl[buf][kk * 512], 16, 0, 0);                            \
    }

    #define VM12 asm volatile("s_waitcnt vmcnt(12)" ::: "memory");

    // Prologue: stage halves 0,1,2 into bufs 0,1,2 (12 loads in flight)
    STAGE_HP(0, 0)
    STAGE_HP(1, 1)
    STAGE_HP(2, 2)

    // ---- Load A fragments (4 Mtiles x 8 k-steps), fp32 -> bf16, keep in regs
    bf16x8 a[MT][KT];
    #pragma unroll
    for (int m = 0; m < MT; ++m) {
        const float* xr = x + (row0 + m * 16 + c) * D + g * 8;
        #pragma unroll
        for (int kt = 0; kt < KT; ++kt) {
            float4 v0 = *(const float4*)(xr + kt * 32);
            float4 v1 = *(const float4*)(xr + kt * 32 + 4);
            bf16x8 t;
            t[0] = f2bf(v0.x); t[1] = f2bf(v0.y); t[2] = f2bf(v0.z); t[3] = f2bf(v0.w);
            t[4] = f2bf(v1.x); t[5] = f2bf(v1.y); t[6] = f2bf(v1.z); t[7] = f2bf(v1.w);
            a[m][kt] = t;
        }
    }

    float lps[MT][4];
    #pragma unroll
    for (int m = 0; m < MT; ++m)
        #pragma unroll
        for (int r = 0; r < 4; ++r) lps[m][r] = 0.0f;

    f32x4 accA[MT], accB[MT];

    // One half-tile (4 kt) from ring buffer `buf` into accv; ktb = 0 or 4.
    #define HALF(buf, accv, ktb) {                                             \
        _Pragma("unroll")                                                      \
        for (int kk = 0; kk < 4; ++kk) {                                       \
            bf16x8 b = *(const bf16x8*)&Bl[buf][kk * 512 + lane * 8];          \
            _Pragma("unroll")                                                  \
            for (int m = 0; m < MT; ++m)                                       \
                accv[m] = __builtin_amdgcn_mfma_f32_16x16x32_bf16(             \
                             a[m][(ktb) + kk], b, accv[m], 0, 0, 0);           \
        }                                                                      \
    }

    #define ZERO(accv) {                                                       \
        _Pragma("unroll")                                                      \
        for (int m = 0; m < MT; ++m)                                           \
            _Pragma("unroll")                                                  \
            for (int r = 0; r < 4; ++r) accv[m][r] = 0.0f;                     \
    }

    #define TANH_(accv, ntv) {                                                 \
        float2 bwv = bw[(ntv) * 16 + c];                                       \
        _Pragma("unroll")                                                      \
        for (int m = 0; m < MT; ++m)                                           \
            _Pragma("unroll")                                                  \
            for (int r = 0; r < 4; ++r) {                                      \
                float z = __builtin_fmaf(accv[m][r], 2.0f, bwv.x);             \
                float e = __expf(z);                                           \
                float rr = rcp_fast(e + 1.0f);                                 \
                lps[m][r] = __builtin_fmaf(bwv.y, rr, lps[m][r]);              \
            }                                                                  \
    }

    // ---- Main loop: 16 iters x 2 nt (4 halves). Ring bufs are compile-time:
    // consume 0,1,2,3; stage 3,0,1,2. Invariant: before consuming half h,
    // halves h..h+3 are issued (16 loads); VM12 -> h's 4 loads have landed.
    for (int it = 0; it < 16; ++it) {
        const int h0 = 4 * it;
        STAGE_HP(3, h0 + 3)
        VM12
        ZERO(accA)
        HALF(0, accA, 0)
        STAGE_HP(0, h0 + 4)
        VM12
        HALF(1, accA, 4)
        if (it > 0) TANH_(accB, 2 * it - 1)
        STAGE_HP(1, h0 + 5)
        VM12
        ZERO(accB)
        HALF(2, accB, 0)
        STAGE_HP(2, h0 + 6)
        VM12
        HALF(3, accB, 4)
        TANH_(accA, 2 * it)
    }
    TANH_(accB, 31)

    // ---- Reduce partials over 16 cols; softmax(sigmoid); weighted output
    const float brv = br[0];
    const float S = Ssum[0];
    #pragma unroll
    for (int m = 0; m < MT; ++m) {
        float l0 = lps[m][0], l1 = lps[m][1], l2 = lps[m][2], l3 = lps[m][3];
        #pragma unroll
        for (int off = 1; off < 16; off <<= 1) {
            l0 += __shfl_xor(l0, off, 64);
            l1 += __shfl_xor(l1, off, 64);
            l2 += __shfl_xor(l2, off, 64);
            l3 += __shfl_xor(l3, off, 64);
        }
        float g0 = S - 2.0f * l0 + brv;
        float g1 = S - 2.0f * l1 + brv;
        float g2 = S - 2.0f * l2 + brv;
        float g3 = S - 2.0f * l3 + brv;
        float s0 = rcp_fast(1.0f + __expf(-g0));
        float s1 = rcp_fast(1.0f + __expf(-g1));
        float s2 = rcp_fast(1.0f + __expf(-g2));
        float s3 = rcp_fast(1.0f + __expf(-g3));
        float e0 = __expf(s0), e1 = __expf(s1), e2 = __expf(s2), e3 = __expf(s3);
        float inv = rcp_fast(e0 + e1 + e2 + e3);
        float w0 = e0 * inv, w1 = e1 * inv, w2 = e2 * inv, w3 = e3 * inv;

        // window = rows [wrow, wrow+3]; lane-group g owns window g of this Mtile
        // lane stores cols [c*4 + q*64 ..+3]: 16 lanes -> 256B contiguous runs
        const long wrow = row0 + m * 16 + g * 4;
        const long W = wrow >> 2;
        const float* xw = x + wrow * D + c * 4;
        float* op = out + W * D + c * 4;
        #pragma unroll
        for (int q = 0; q < 4; ++q) {
            float4 r0 = *(const float4*)(xw + 0 * D + q * 64);
            float4 r1 = *(const float4*)(xw + 1 * D + q * 64);
            float4 r2 = *(const float4*)(xw + 2 * D + q * 64);
            float4 r3 = *(const float4*)(xw + 3 * D + q * 64);
            float4 oo;
            oo.x = w0 * r0.x + w1 * r1.x + w2 * r2.x + w3 * r3.x;
            oo.y = w0 * r0.y + w1 * r1.y + w2 * r2.y + w3 * r3.y;
            oo.z = w0 * r0.z + w1 * r1.z + w2 * r2.z + w3 * r3.z;
            oo.w = w0 * r0.w + w1 * r1.w + w2 * r2.w + w3 * r3.w;
            *(float4*)(op + q * 64) = oo;
        }
    }
}

extern "C" void kernel_launch(void* const* d_in, const int* in_sizes, int n_in,
                              void* d_out, int out_size, void* d_ws, size_t ws_size,
                              hipStream_t stream) {
    const float* x  = (const float*)d_in[0];
    const float* We = (const float*)d_in[1];
    const float* be = (const float*)d_in[2];
    const float* Wr = (const float*)d_in[3];
    const float* br = (const float*)d_in[4];
    float* out = (float*)d_out;

    char* ws = (char*)d_ws;
    short*  Bh   = (short*)ws;                    // 262144 B
    float2* bwp  = (float2*)(ws + 262144);        // 4096 B
    float*  Ssum = (float*)(ws + 262144 + 4096);  // 4 B

    prepack_B<<<NH * D / 256, 256, 0, stream>>>(We, be, Wr, Bh, bwp, Ssum);

    const int blocks = ROWS_TOTAL / ROWS_PER_BLOCK;   // 4096
    softpool_main<<<blocks, 64, 0, stream>>>(x, Bh, bwp, br, Ssum, out);
}